// Round 12
// baseline (651.824 us; speedup 1.0000x reference)
//
#include <hip/hip_runtime.h>

#define NN 100000
#define NE 1600000
#define NB 391        // ceil(NN/256)
#define NS 13         // src slices: slice = src >> 13
#define NSP1 14
#define SLICE_SHIFT 13

// ============== build: per-(dst,slice) bucketed CSR (unchanged from R11) ==============

__global__ __launch_bounds__(256) void hist2_k(const int* __restrict__ ei,
                                               int* __restrict__ deg2) {
    int e = blockIdx.x * 256 + threadIdx.x;
    int src = ei[e];
    int dst = ei[NE + e];
    atomicAdd(&deg2[dst * NS + (src >> SLICE_SHIFT)], 1);
}

__global__ __launch_bounds__(256) void rowsum_k(const int* __restrict__ deg2,
                                                int* __restrict__ deg) {
    int i = blockIdx.x * 256 + threadIdx.x;
    if (i < NN) {
        int s = 0;
#pragma unroll
        for (int k = 0; k < NS; ++k) s += deg2[i * NS + k];
        deg[i] = s;
    }
}

__global__ __launch_bounds__(256) void scan1_k(const int* __restrict__ deg,
                                               int* __restrict__ scanned,
                                               int* __restrict__ bsums) {
    __shared__ int tmp[256];
    int i = blockIdx.x * 256 + threadIdx.x;
    int v = (i < NN) ? deg[i] : 0;
    tmp[threadIdx.x] = v;
    __syncthreads();
#pragma unroll
    for (int off = 1; off < 256; off <<= 1) {
        int t = (threadIdx.x >= off) ? tmp[threadIdx.x - off] : 0;
        __syncthreads();
        tmp[threadIdx.x] += t;
        __syncthreads();
    }
    if (i < NN) scanned[i] = tmp[threadIdx.x];
    if (threadIdx.x == 255) bsums[blockIdx.x] = tmp[255];
}

__global__ __launch_bounds__(512) void scan2_k(int* __restrict__ bsums) {
    __shared__ int tmp[512];
    int v = (threadIdx.x < NB) ? bsums[threadIdx.x] : 0;
    tmp[threadIdx.x] = v;
    __syncthreads();
#pragma unroll
    for (int off = 1; off < 512; off <<= 1) {
        int t = (threadIdx.x >= off) ? tmp[threadIdx.x - off] : 0;
        __syncthreads();
        tmp[threadIdx.x] += t;
        __syncthreads();
    }
    if (threadIdx.x < NB) bsums[threadIdx.x] = tmp[threadIdx.x];
}

__global__ __launch_bounds__(256) void scan3b_k(const int* __restrict__ scanned,
                                                const int* __restrict__ bsums,
                                                const int* __restrict__ deg,
                                                const int* __restrict__ deg2,
                                                int* __restrict__ P) {
    int i = blockIdx.x * 256 + threadIdx.x;
    if (i < NN) {
        int incl = scanned[i] + (blockIdx.x ? bsums[blockIdx.x - 1] : 0);
        int run = incl - deg[i];
        P[i * NSP1 + 0] = run;
#pragma unroll
        for (int s = 0; s < NS; ++s) {
            P[i * NSP1 + s + 1] = run;
            run += deg2[i * NS + s];
        }
    }
}

__global__ __launch_bounds__(256) void fill2_k(const int* __restrict__ ei,
                                               int* __restrict__ P,
                                               int* __restrict__ col) {
    int e = blockIdx.x * 256 + threadIdx.x;
    int src = ei[e];
    int dst = ei[NE + e];
    int pos = atomicAdd(&P[dst * NSP1 + (src >> SLICE_SHIFT) + 1], 1);
    col[pos] = src;
}

// ============ layer 1: pipelined reg-ILP gather(x) + MLP1 -> h ============
// one wave per node; parity halves take alternate edges; 4-wide groups,
// 2-stage A/B pipeline (next group's loads in flight while consuming current).
__global__ __launch_bounds__(256) void fused1(const float* __restrict__ x,
                                              const int* __restrict__ P,
                                              const int* __restrict__ col,
                                              const float* __restrict__ W1,
                                              const float* __restrict__ b1,
                                              const float* __restrict__ W2,
                                              const float* __restrict__ b2,
                                              float* __restrict__ h) {
    __shared__ float W1s[32 * 64];
    __shared__ float W2s[64 * 64];
    __shared__ float b1s[64];
    __shared__ float b2s[64];
    for (int i = threadIdx.x; i < 32 * 64; i += 256) W1s[i] = W1[i];
    for (int i = threadIdx.x; i < 64 * 64; i += 256) W2s[i] = W2[i];
    if (threadIdx.x < 64) {
        b1s[threadIdx.x] = b1[threadIdx.x];
        b2s[threadIdx.x] = b2[threadIdx.x];
    }
    __syncthreads();

    int lane = threadIdx.x & 63;
    int c = lane & 31;
    int p = lane >> 5;
    int gw = blockIdx.x * 4 + (threadIdx.x >> 6);
    int nwaves = gridDim.x * 4;

    for (int node = gw; node < NN; node += nwaves) {
        int s0 = P[node * NSP1];
        int s1 = P[node * NSP1 + NS];
        float self = x[(size_t)node * 32 + c];

        float a0 = 0.f, a1 = 0.f, a2 = 0.f, a3 = 0.f;
        int e = s0 + p;                                  // this parity's edges: e, e+2, ...
        int cnt = (s1 > e) ? ((s1 - e + 1) >> 1) : 0;    // edges for this parity
        int G = cnt >> 2;                                // full 4-edge groups

        if (G > 0) {
            int cA0 = col[e],     cA1 = col[e + 2], cA2 = col[e + 4], cA3 = col[e + 6];
            float uA0 = x[(size_t)cA0 * 32 + c];
            float uA1 = x[(size_t)cA1 * 32 + c];
            float uA2 = x[(size_t)cA2 * 32 + c];
            float uA3 = x[(size_t)cA3 * 32 + c];
            e += 8;
            int g = 1;
            for (; g + 1 < G; g += 2) {
                int cB0 = col[e],     cB1 = col[e + 2], cB2 = col[e + 4], cB3 = col[e + 6];
                float uB0 = x[(size_t)cB0 * 32 + c];
                float uB1 = x[(size_t)cB1 * 32 + c];
                float uB2 = x[(size_t)cB2 * 32 + c];
                float uB3 = x[(size_t)cB3 * 32 + c];
                a0 += uA0; a1 += uA1; a2 += uA2; a3 += uA3;   // waits A only; B in flight
                int cC0 = col[e + 8], cC1 = col[e + 10], cC2 = col[e + 12], cC3 = col[e + 14];
                uA0 = x[(size_t)cC0 * 32 + c];
                uA1 = x[(size_t)cC1 * 32 + c];
                uA2 = x[(size_t)cC2 * 32 + c];
                uA3 = x[(size_t)cC3 * 32 + c];
                a0 += uB0; a1 += uB1; a2 += uB2; a3 += uB3;   // waits B; new A in flight
                e += 16;
            }
            if (g < G) {
                int cB0 = col[e],     cB1 = col[e + 2], cB2 = col[e + 4], cB3 = col[e + 6];
                float uB0 = x[(size_t)cB0 * 32 + c];
                float uB1 = x[(size_t)cB1 * 32 + c];
                float uB2 = x[(size_t)cB2 * 32 + c];
                float uB3 = x[(size_t)cB3 * 32 + c];
                a0 += uA0; a1 += uA1; a2 += uA2; a3 += uA3;
                a0 += uB0; a1 += uB1; a2 += uB2; a3 += uB3;
                e += 8;
            } else {
                a0 += uA0; a1 += uA1; a2 += uA2; a3 += uA3;
            }
        }
        for (; e < s1; e += 2)
            a0 += x[(size_t)col[e] * 32 + c];

        float acc = (a0 + a1) + (a2 + a3);
        acc += __shfl_xor(acc, 32);
        float aval = acc + self;

        float s = b1s[lane];
#pragma unroll
        for (int i = 0; i < 32; ++i)
            s += __shfl(aval, i) * W1s[i * 64 + lane];
        float t = fmaxf(s, 0.f);

        float s2 = b2s[lane];
#pragma unroll
        for (int j = 0; j < 64; ++j)
            s2 += __shfl(t, j) * W2s[j * 64 + lane];
        h[(size_t)node * 64 + lane] = fmaxf(s2, 0.f);
    }
}

// ============ layer 2: pipelined reg-ILP gather(h) + MLP2 -> out ============
// one wave per node; 8-wide groups, 2-stage A/B pipeline (16 loads in flight).
__global__ __launch_bounds__(256) void fused2(const float* __restrict__ h,
                                              const int* __restrict__ P,
                                              const int* __restrict__ col,
                                              const float* __restrict__ W3,
                                              const float* __restrict__ b3,
                                              const float* __restrict__ W4,
                                              const float* __restrict__ b4,
                                              float* __restrict__ out) {
    __shared__ float W3s[64 * 64];
    __shared__ float W4s[64 * 32];
    __shared__ float b3s[64];
    __shared__ float b4s[32];
    for (int i = threadIdx.x; i < 64 * 64; i += 256) W3s[i] = W3[i];
    for (int i = threadIdx.x; i < 64 * 32; i += 256) W4s[i] = W4[i];
    if (threadIdx.x < 64) b3s[threadIdx.x] = b3[threadIdx.x];
    if (threadIdx.x < 32) b4s[threadIdx.x] = b4[threadIdx.x];
    __syncthreads();

    int lane = threadIdx.x & 63;
    int gw = blockIdx.x * 4 + (threadIdx.x >> 6);
    int nwaves = gridDim.x * 4;

    for (int node = gw; node < NN; node += nwaves) {
        int s0 = P[node * NSP1];
        int s1 = P[node * NSP1 + NS];
        float self = h[(size_t)node * 64 + lane];

        float a0 = 0.f, a1 = 0.f, a2 = 0.f, a3 = 0.f;
        float a4 = 0.f, a5 = 0.f, a6 = 0.f, a7 = 0.f;
        int e = s0;
        int G = (s1 - s0) >> 3;

        if (G > 0) {
            int cA0 = col[e],     cA1 = col[e + 1], cA2 = col[e + 2], cA3 = col[e + 3];
            int cA4 = col[e + 4], cA5 = col[e + 5], cA6 = col[e + 6], cA7 = col[e + 7];
            float uA0 = h[(size_t)cA0 * 64 + lane];
            float uA1 = h[(size_t)cA1 * 64 + lane];
            float uA2 = h[(size_t)cA2 * 64 + lane];
            float uA3 = h[(size_t)cA3 * 64 + lane];
            float uA4 = h[(size_t)cA4 * 64 + lane];
            float uA5 = h[(size_t)cA5 * 64 + lane];
            float uA6 = h[(size_t)cA6 * 64 + lane];
            float uA7 = h[(size_t)cA7 * 64 + lane];
            e += 8;
            int g = 1;
            for (; g + 1 < G; g += 2) {
                int cB0 = col[e],     cB1 = col[e + 1], cB2 = col[e + 2], cB3 = col[e + 3];
                int cB4 = col[e + 4], cB5 = col[e + 5], cB6 = col[e + 6], cB7 = col[e + 7];
                float uB0 = h[(size_t)cB0 * 64 + lane];
                float uB1 = h[(size_t)cB1 * 64 + lane];
                float uB2 = h[(size_t)cB2 * 64 + lane];
                float uB3 = h[(size_t)cB3 * 64 + lane];
                float uB4 = h[(size_t)cB4 * 64 + lane];
                float uB5 = h[(size_t)cB5 * 64 + lane];
                float uB6 = h[(size_t)cB6 * 64 + lane];
                float uB7 = h[(size_t)cB7 * 64 + lane];
                a0 += uA0; a1 += uA1; a2 += uA2; a3 += uA3;   // waits A; B in flight
                a4 += uA4; a5 += uA5; a6 += uA6; a7 += uA7;
                int cC0 = col[e + 8],  cC1 = col[e + 9],  cC2 = col[e + 10], cC3 = col[e + 11];
                int cC4 = col[e + 12], cC5 = col[e + 13], cC6 = col[e + 14], cC7 = col[e + 15];
                uA0 = h[(size_t)cC0 * 64 + lane];
                uA1 = h[(size_t)cC1 * 64 + lane];
                uA2 = h[(size_t)cC2 * 64 + lane];
                uA3 = h[(size_t)cC3 * 64 + lane];
                uA4 = h[(size_t)cC4 * 64 + lane];
                uA5 = h[(size_t)cC5 * 64 + lane];
                uA6 = h[(size_t)cC6 * 64 + lane];
                uA7 = h[(size_t)cC7 * 64 + lane];
                a0 += uB0; a1 += uB1; a2 += uB2; a3 += uB3;   // waits B; new A in flight
                a4 += uB4; a5 += uB5; a6 += uB6; a7 += uB7;
                e += 16;
            }
            if (g < G) {
                int cB0 = col[e],     cB1 = col[e + 1], cB2 = col[e + 2], cB3 = col[e + 3];
                int cB4 = col[e + 4], cB5 = col[e + 5], cB6 = col[e + 6], cB7 = col[e + 7];
                float uB0 = h[(size_t)cB0 * 64 + lane];
                float uB1 = h[(size_t)cB1 * 64 + lane];
                float uB2 = h[(size_t)cB2 * 64 + lane];
                float uB3 = h[(size_t)cB3 * 64 + lane];
                float uB4 = h[(size_t)cB4 * 64 + lane];
                float uB5 = h[(size_t)cB5 * 64 + lane];
                float uB6 = h[(size_t)cB6 * 64 + lane];
                float uB7 = h[(size_t)cB7 * 64 + lane];
                a0 += uA0; a1 += uA1; a2 += uA2; a3 += uA3;
                a4 += uA4; a5 += uA5; a6 += uA6; a7 += uA7;
                a0 += uB0; a1 += uB1; a2 += uB2; a3 += uB3;
                a4 += uB4; a5 += uB5; a6 += uB6; a7 += uB7;
                e += 8;
            } else {
                a0 += uA0; a1 += uA1; a2 += uA2; a3 += uA3;
                a4 += uA4; a5 += uA5; a6 += uA6; a7 += uA7;
            }
        }
        for (; e < s1; ++e)
            a0 += h[(size_t)col[e] * 64 + lane];

        float aval = (((a0 + a1) + (a2 + a3)) + ((a4 + a5) + (a6 + a7))) + self;

        float s = b3s[lane];
#pragma unroll
        for (int i = 0; i < 64; ++i)
            s += __shfl(aval, i) * W3s[i * 64 + lane];
        float t = fmaxf(s, 0.f);

        float s2 = b4s[lane & 31];
#pragma unroll
        for (int j = 0; j < 64; ++j)
            s2 += __shfl(t, j) * W4s[j * 32 + (lane & 31)];
        if (lane < 32) out[(size_t)node * 32 + lane] = s2;
    }
}

extern "C" void kernel_launch(void* const* d_in, const int* in_sizes, int n_in,
                              void* d_out, int out_size, void* d_ws, size_t ws_size,
                              hipStream_t stream) {
    const float* x  = (const float*)d_in[0];
    const int*   ei = (const int*)d_in[1];
    const float* W1 = (const float*)d_in[2];
    const float* b1 = (const float*)d_in[3];
    const float* W2 = (const float*)d_in[4];
    const float* b2 = (const float*)d_in[5];
    const float* W3 = (const float*)d_in[6];
    const float* b3 = (const float*)d_in[7];
    const float* W4 = (const float*)d_in[8];
    const float* b4 = (const float*)d_in[9];
    float* out = (float*)d_out;

    char* ws = (char*)d_ws;
    float* h   = (float*)ws;                          ws += (size_t)NN * 64 * 4;       // 25.6 MB
    int*   col = (int*)ws;                            ws += (size_t)NE * 4;            // 6.4 MB
    int*   P   = (int*)ws;                            ws += (size_t)NN * NSP1 * 4;     // 5.6 MB

    // build-time arrays overlay the h region (dead before fused1 writes h)
    char* ov = (char*)h;
    int* deg2    = (int*)ov;                          ov += (size_t)NN * NS * 4;       // 5.2 MB
    int* deg     = (int*)ov;                          ov += (size_t)NN * 4;
    int* scanned = (int*)ov;                          ov += (size_t)NN * 4;
    int* bsums   = (int*)ov;                          ov += (size_t)NB * 4;

    // ---- slice-bucketed CSR build ----
    hipMemsetAsync(deg2, 0, (size_t)NN * NS * 4, stream);
    hist2_k<<<NE / 256, 256, 0, stream>>>(ei, deg2);
    rowsum_k<<<NB, 256, 0, stream>>>(deg2, deg);
    scan1_k<<<NB, 256, 0, stream>>>(deg, scanned, bsums);
    scan2_k<<<1, 512, 0, stream>>>(bsums);
    scan3b_k<<<NB, 256, 0, stream>>>(scanned, bsums, deg, deg2, P);
    fill2_k<<<NE / 256, 256, 0, stream>>>(ei, P, col);

    // ---- fused layers: 2-stage pipelined gather over slice-sorted rows ----
    fused1<<<1536, 256, 0, stream>>>(x, P, col, W1, b1, W2, b2, h);
    fused2<<<1536, 256, 0, stream>>>(h, P, col, W3, b3, W4, b4, out);
}